// Round 1
// baseline (633.684 us; speedup 1.0000x reference)
//
#include <hip/hip_runtime.h>
#include <math.h>

#define HID 256

// degree tables: d1[i]=1/sqrt(i+1) (GCN layers), d2[i]=1/sqrt(1+0.5i) (op conv)
__device__ __forceinline__ float d1c(int i) { return 1.0f / sqrtf((float)(i + 1)); }
__device__ __forceinline__ float d2c(int i) { return 1.0f / sqrtf(1.0f + 0.5f * (float)i); }

// in-place descending prefix mix: v[r] = sum_{i<=r} d1[i]*d1[r]*v[i]  (one 7-row graph, 4 cols)
__device__ __forceinline__ void mixA1_4(float (&v)[7][4]) {
#pragma unroll
    for (int r = 6; r >= 0; --r) {
        float t[4] = {0, 0, 0, 0};
#pragma unroll
        for (int i = 0; i <= r; ++i) {
            const float c = d1c(i) * d1c(r);
#pragma unroll
            for (int j = 0; j < 4; ++j) t[j] = fmaf(c, v[i][j], t[j]);
        }
#pragma unroll
        for (int j = 0; j < 4; ++j) v[r][j] = t[j];
    }
}

// Store one graph's v[7 rows][4 k] into P^T[k][32 slots]; rows at chunk cb (rows 0-3)
// and cb+1 (rows 4-6 + pad). Chunk-swizzle: physical chunk = logical ^ ((k>>3)&7).
// cb is a multiple of 2 and (cb^key)^1 == (cb+1)^key, so second write is idx^4.
__device__ __forceinline__ void storePT4(const float (&v)[7][4], float* shp,
                                         int kbase, int cb) {
#pragma unroll
    for (int j = 0; j < 4; ++j) {
        const int k   = kbase + j;
        const int key = (k >> 3) & 7;
        const int i0  = (k << 5) + ((cb ^ key) << 2);
        *(float4*)(shp + i0)       = make_float4(v[0][j], v[1][j], v[2][j], v[3][j]);
        *(float4*)(shp + (i0 ^ 4)) = make_float4(v[4][j], v[5][j], v[6][j], 0.0f);
    }
}

// accA/accB[7][4] += P^T[k][rows of graphs A,B] (full-wave LDS broadcasts)
//                    * W[k][c0..c0+3] (one coalesced float4/lane, wave covers 256 cols,
//                    ZERO duplication). cb = 4*wave: chunks cb..cb+1 = graph A, cb+2..cb+3 = B.
__device__ __forceinline__ void gemm_k2(float (&accA)[7][4], float (&accB)[7][4],
                                        const float* __restrict__ wb,
                                        const float* shp, int cb) {
    for (int k0 = 0; k0 < HID; k0 += 8) {
        const int key = (k0 >> 3) & 7;
        const int iA  = (k0 << 5) + ((cb ^ key) << 2);       // iA^4 = A rows 4-6
        const int iB  = iA ^ 8;                              // (cb+2)^key, cb%4==0
#pragma unroll
        for (int kk = 0; kk < 8; ++kk) {
            const int o = kk << 5;
            float4 a0 = *(const float4*)(shp + iA + o);
            float4 a1 = *(const float4*)(shp + (iA ^ 4) + o);
            float4 b0 = *(const float4*)(shp + iB + o);
            float4 b1 = *(const float4*)(shp + (iB ^ 4) + o);
            float4 w4 = *(const float4*)(wb + (long)(k0 + kk) * HID);
            const float pa[7] = {a0.x, a0.y, a0.z, a0.w, a1.x, a1.y, a1.z};
            const float pb[7] = {b0.x, b0.y, b0.z, b0.w, b1.x, b1.y, b1.z};
#pragma unroll
            for (int r = 0; r < 7; ++r) {
                accA[r][0] = fmaf(pa[r], w4.x, accA[r][0]);
                accA[r][1] = fmaf(pa[r], w4.y, accA[r][1]);
                accA[r][2] = fmaf(pa[r], w4.z, accA[r][2]);
                accA[r][3] = fmaf(pa[r], w4.w, accA[r][3]);
                accB[r][0] = fmaf(pb[r], w4.x, accB[r][0]);
                accB[r][1] = fmaf(pb[r], w4.y, accB[r][1]);
                accB[r][2] = fmaf(pb[r], w4.z, accB[r][2]);
                accB[r][3] = fmaf(pb[r], w4.w, accB[r][3]);
            }
        }
    }
}

// 128 threads = 2 waves; each wave owns TWO graphs (14 rows) across all 256 cols
// (4 cols/lane). vs previous version: W global traffic per FLOP halved AND the 2x
// intra-wave duplication removed (1 coalesced 1KB W load per 56 FMAs). LDS (32KB),
// accumulator count (56) and occupancy unchanged; P^T reads are uniform-address
// full-wave broadcasts (conflict-free).
// Identities: avg_scores==0.5 (2-way softmax); A*(X@W)==(A*X)@W;
// deg1[j]=j+1, deg2[j]=1+0.5j (fixed 7-node upper-tri DAG).
__global__ __launch_bounds__(128, 2)
void nas_fused(const float* __restrict__ X,
               const float* __restrict__ W1, const float* __restrict__ b1,
               const float* __restrict__ W2, const float* __restrict__ b2,
               const float* __restrict__ Wm, const float* __restrict__ bm,
               const float* __restrict__ g_op,
               float* __restrict__ out)
{
    __shared__ float sh[HID * 32];   // 32 KB: P^T[k][32 slots]; reused for pm bounce

    const int tid = threadIdx.x;
    const int w   = tid >> 6;        // wave in block, 0..1
    const int l   = tid & 63;        // lane
    const int c0  = l << 2;          // this lane's 4 cols (== its 4 k-rows next layer)
    const int cb  = w << 2;          // chunk base: graphs 2w,2w+1 at chunks 4w..4w+3
    const int gA  = w << 1, gB = gA | 1;
    const long node0 = (long)blockIdx.x * 28;

    float accA[7][4], accB[7][4];

    // ---------- stage 1: load X (2 graphs x 7 rows x 4 cols), A1-mix, write P1^T ----------
    {
        const float* xa = X + (node0 + gA * 7) * HID + c0;
        const float* xb = X + (node0 + gB * 7) * HID + c0;
#pragma unroll
        for (int r = 0; r < 7; ++r) {
            float4 a = *(const float4*)(xa + (long)r * HID);
            float4 b = *(const float4*)(xb + (long)r * HID);
            accA[r][0] = a.x; accA[r][1] = a.y; accA[r][2] = a.z; accA[r][3] = a.w;
            accB[r][0] = b.x; accB[r][1] = b.y; accB[r][2] = b.z; accB[r][3] = b.w;
        }
        mixA1_4(accA);
        mixA1_4(accB);
        storePT4(accA, sh, c0, cb);
        storePT4(accB, sh, c0, cb + 2);
    }
    __syncthreads();

    // ---------- layer 1: acc = P1 @ W1 ----------
#pragma unroll
    for (int r = 0; r < 7; ++r)
#pragma unroll
        for (int j = 0; j < 4; ++j) { accA[r][j] = 0.0f; accB[r][j] = 0.0f; }
    gemm_k2(accA, accB, W1 + c0, sh, cb);

    {   // +b1, relu (graphs share cols -> same bias)
        float4 bb = *(const float4*)(b1 + c0);
        const float bia[4] = {bb.x, bb.y, bb.z, bb.w};
#pragma unroll
        for (int r = 0; r < 7; ++r)
#pragma unroll
            for (int j = 0; j < 4; ++j) {
                accA[r][j] = fmaxf(accA[r][j] + bia[j], 0.0f);
                accB[r][j] = fmaxf(accB[r][j] + bia[j], 0.0f);
            }
    }
    mixA1_4(accA);                    // P2 = A1 * H1
    mixA1_4(accB);
    __syncthreads();                  // everyone done READING P1
    storePT4(accA, sh, c0, cb);       // acc dead here -> no dual-live set
    storePT4(accB, sh, c0, cb + 2);
    __syncthreads();

    // ---------- layer 2: acc = P2 @ W2 ----------
#pragma unroll
    for (int r = 0; r < 7; ++r)
#pragma unroll
        for (int j = 0; j < 4; ++j) { accA[r][j] = 0.0f; accB[r][j] = 0.0f; }
    gemm_k2(accA, accB, W2 + c0, sh, cb);

    {   // +b2, relu
        float4 bb = *(const float4*)(b2 + c0);
        const float bia[4] = {bb.x, bb.y, bb.z, bb.w};
#pragma unroll
        for (int r = 0; r < 7; ++r)
#pragma unroll
            for (int j = 0; j < 4; ++j) {
                accA[r][j] = fmaxf(accA[r][j] + bia[j], 0.0f);
                accB[r][j] = fmaxf(accB[r][j] + bia[j], 0.0f);
            }
    }

    // ---------- pm = (H2 @ Wm) partials over this lane's 4 cols ----------
    float pmA[7][5], pmB[7][5];
#pragma unroll
    for (int r = 0; r < 7; ++r)
#pragma unroll
        for (int p = 0; p < 5; ++p) { pmA[r][p] = 0.0f; pmB[r][p] = 0.0f; }
#pragma unroll
    for (int j = 0; j < 4; ++j) {
        const float* wr = Wm + (c0 + j) * 5;
        float wv[5];
#pragma unroll
        for (int p = 0; p < 5; ++p) wv[p] = wr[p];
#pragma unroll
        for (int r = 0; r < 7; ++r)
#pragma unroll
            for (int p = 0; p < 5; ++p) {
                pmA[r][p] = fmaf(accA[r][j], wv[p], pmA[r][p]);
                pmB[r][p] = fmaf(accB[r][j], wv[p], pmB[r][p]);
            }
    }
    // butterfly over all 64 lanes (cols now span the whole wave)
#pragma unroll
    for (int m = 32; m >= 1; m >>= 1)
#pragma unroll
        for (int r = 0; r < 7; ++r)
#pragma unroll
            for (int p = 0; p < 5; ++p) {
                pmA[r][p] += __shfl_xor(pmA[r][p], m, 64);
                pmB[r][p] += __shfl_xor(pmB[r][p], m, 64);
            }

    __syncthreads();                  // all k-loop reads of sh complete
    // one lane per graph stages full pm (static register indices only)
    if (l == 0) {
#pragma unroll
        for (int r = 0; r < 7; ++r)
#pragma unroll
            for (int p = 0; p < 5; ++p) sh[gA * 35 + r * 5 + p] = pmA[r][p];
    }
    if (l == 32) {
#pragma unroll
        for (int r = 0; r < 7; ++r)
#pragma unroll
            for (int p = 0; p < 5; ++p) sh[gB * 35 + r * 5 + p] = pmB[r][p];
    }
    __syncthreads();

    if (tid < 28) {                   // finalize node node0 + tid
        const int gg = tid / 7;
        const int rr = tid - gg * 7;
        const float* ps = sh + gg * 35;
        const float d2r = d2c(rr);
        float op[5];
#pragma unroll
        for (int p = 0; p < 5; ++p) op[p] = bm[p];
#pragma unroll
        for (int i = 0; i < 7; ++i) {
            // A2 prefix weight: self d2r^2, incoming (i<rr) 0.5*d2[i]*d2r, else 0
            const float wgt = (i > rr) ? 0.0f
                            : (((i < rr) ? 0.5f : 1.0f) * d2c(i) * d2r);
#pragma unroll
            for (int p = 0; p < 5; ++p)
                op[p] = fmaf(wgt, ps[i * 5 + p], op[p]);
        }
        const float* gp = g_op + (node0 + tid) * 5;
        float best = op[0] + gp[0];
        int bi = 0;
#pragma unroll
        for (int p = 1; p < 5; ++p) {
            float u = op[p] + gp[p];
            if (u > best) { best = u; bi = p; }   // strict > == jnp.argmax first-max
        }
        float* o = out + (node0 + tid) * 5;
#pragma unroll
        for (int p = 0; p < 5; ++p) o[p] = (p == bi) ? 1.0f : 0.0f;
    }
}

extern "C" void kernel_launch(void* const* d_in, const int* in_sizes, int n_in,
                              void* d_out, int out_size, void* d_ws, size_t ws_size,
                              hipStream_t stream)
{
    const float* X   = (const float*)d_in[0];
    // d_in[1] edge_index, d_in[2] batch: compile-time-constant structure
    const float* W1  = (const float*)d_in[3];
    const float* b1  = (const float*)d_in[4];
    const float* W2  = (const float*)d_in[5];
    const float* b2  = (const float*)d_in[6];
    // d_in[7] We, d_in[8] be, d_in[11] g_edge: dead (avg_scores == 0.5)
    const float* Wm  = (const float*)d_in[9];
    const float* bm  = (const float*)d_in[10];
    const float* gop = (const float*)d_in[12];
    float* out = (float*)d_out;

    const int N       = in_sizes[0] / HID;  // 140000 nodes
    const int ngraph  = N / 7;              // 20000
    const int nblocks = ngraph / 4;         // 5000 blocks of 128 threads

    nas_fused<<<nblocks, 128, 0, stream>>>(X, W1, b1, W2, b2, Wm, bm, gop, out);
}

// Round 2
// 441.192 us; speedup vs baseline: 1.4363x; 1.4363x over previous
//
#include <hip/hip_runtime.h>
#include <math.h>

#define HID 256

typedef __attribute__((ext_vector_type(8))) short v8s;   // 8 bf16 (4 VGPRs)
typedef __attribute__((ext_vector_type(4))) float v4f;   // MFMA accumulator

__device__ __forceinline__ float d1c(int i){ return 1.0f/sqrtf((float)(i+1)); }
__device__ __forceinline__ float d2c(int i){ return 1.0f/sqrtf(1.0f+0.5f*(float)i); }

// round-to-nearest-even float -> bf16 (bit pattern)
__device__ __forceinline__ unsigned short f2bf(float x){
    unsigned u = __float_as_uint(x);
    u += 0x7fffu + ((u>>16)&1u);
    return (unsigned short)(u>>16);
}
__device__ __forceinline__ float bf2f(unsigned short b){
    return __uint_as_float(((unsigned)b)<<16);
}

// in-place descending prefix mix: v[r] = sum_{i<=r} d1[i]*d1[r]*v[i]
__device__ __forceinline__ void mixA1_4(float (&v)[7][4]) {
#pragma unroll
    for (int r = 6; r >= 0; --r) {
        float t[4] = {0, 0, 0, 0};
#pragma unroll
        for (int i = 0; i <= r; ++i) {
            const float c = d1c(i) * d1c(r);
#pragma unroll
            for (int j = 0; j < 4; ++j) t[j] = fmaf(c, v[i][j], t[j]);
        }
#pragma unroll
        for (int j = 0; j < 4; ++j) v[r][j] = t[j];
    }
}

// ---------------- prep: pack W1,W2 3-term bf16 splits in B-fragment order ----
// layout: [L(2)][s(3)][k0(8)][nt(16)][lane(64)][e(8)] bf16, linear in tid.
// value = w_s[k0*32 + 8*(lane>>4) + e][nt*16 + (lane&15)]
__global__ void prep_w(const float* __restrict__ W1, const float* __restrict__ W2,
                       unsigned short* __restrict__ outw)
{
    const int tid = blockIdx.x*256 + threadIdx.x;
    if (tid >= 2*3*8*16*64) return;
    const int l  = tid & 63;
    const int c  = tid >> 6;
    const int nt = c & 15;
    const int k0 = (c>>4) & 7;
    const int s  = (c>>7) % 3;
    const int L  = c / (3*8*16);
    const float* W = L ? W2 : W1;
    const int n = nt*16 + (l & 15);
    unsigned short* o = outw + (size_t)tid*8;
#pragma unroll
    for (int e = 0; e < 8; ++e){
        const int k = k0*32 + (l>>4)*8 + e;
        float x = W[k*HID + n];
        unsigned short b0 = f2bf(x); float rr = x - bf2f(b0);
        unsigned short b1 = f2bf(rr); rr -= bf2f(b1);
        unsigned short b2 = f2bf(rr);
        o[e] = (s==0)? b0 : (s==1)? b1 : b2;
    }
}

// ---------------- main fused kernel ----------------------------------------
// 256 threads = 4 waves; 8 graphs (56 rows + 8 pad rows = 4 M-tiles of 16).
// Each wave owns N-tiles {w, 4+w, 8+w, 12+w} (acc[mt][p], ntile = 4p+w).
// GEMMs run on bf16 MFMA with 3-term error-compensated splits (6 products,
// s1+s2<=2, error ~2^-26 — below fp32-reorder noise). Splits staged per
// k-half in LDS (48KB, XOR 16B-slot swizzle); layer outputs redistributed
// through a 16KB quarter-bounce for bias/relu/mix. 64KB LDS -> 2 blocks/CU.
// Permutation-invariant packing: A and B both use slot->k map 8*(l>>4)+e.
__global__ __launch_bounds__(256, 2)
void nas_mfma(const float* __restrict__ X,
              const float* __restrict__ b1, const float* __restrict__ b2,
              const float* __restrict__ Wm, const float* __restrict__ bm,
              const float* __restrict__ g_op,
              const unsigned short* __restrict__ Bw,
              float* __restrict__ out)
{
    __shared__ __align__(16) char smem[49152 + 16384]; // splits[3][64rows][128k] bf16 ; bounce[64][64] f32
    char* sb = smem;
    float* bnc = (float*)(smem + 49152);

    const int t   = threadIdx.x;
    const int w   = t >> 6;          // wave 0..3
    const int l   = t & 63;
    const int l15 = l & 15;
    const int q   = l >> 4;
    const int g   = t >> 5;          // graph 0..7
    const int t31 = t & 31;
    const long node0 = (long)blockIdx.x * 56;

    // write 3-term splits of v[7][4] for k-local cols 4*t31..+3, rows 7g..7g+6.
    // slot swizzle: physical 16B slot = (k>>3) ^ (row&7); contents stay k-ordered.
    auto writeSplits = [&](float (&v)[7][4]){
        const int kl   = 4*t31;
        const int hs   = kl >> 3;          // logical slot
        const int sub8 = (kl & 7) * 2;     // byte offset within slot (0 or 8)
#pragma unroll
        for (int r = 0; r < 7; ++r){
            const int row  = g*7 + r;
            const int slot = hs ^ (row & 7);
            char* p = sb + row*256 + slot*16 + sub8;
            unsigned short h0[4], h1[4], h2[4];
#pragma unroll
            for (int j = 0; j < 4; ++j){
                float x = v[r][j];
                h0[j] = f2bf(x); float rr = x - bf2f(h0[j]);
                h1[j] = f2bf(rr); rr -= bf2f(h1[j]);
                h2[j] = f2bf(rr);
            }
            *(uint2*)(p)         = make_uint2((unsigned)h0[0]|((unsigned)h0[1]<<16),
                                              (unsigned)h0[2]|((unsigned)h0[3]<<16));
            *(uint2*)(p+16384)   = make_uint2((unsigned)h1[0]|((unsigned)h1[1]<<16),
                                              (unsigned)h1[2]|((unsigned)h1[3]<<16));
            *(uint2*)(p+32768)   = make_uint2((unsigned)h2[0]|((unsigned)h2[1]<<16),
                                              (unsigned)h2[2]|((unsigned)h2[3]<<16));
        }
    };

    // one k-half of a split GEMM: acc[mt][p] += sum over 6 products
    auto gemm_half = [&](v4f (&ac)[4][4], const unsigned short* lbase, int h){
#pragma unroll 1
        for (int ks = 0; ks < 4; ++ks){
            const int ksg = h*4 + ks;
            v8s A[3][4];
            const int xorslot = ((ks*4 + q) ^ (l & 7)) << 4;
#pragma unroll
            for (int s = 0; s < 3; ++s)
#pragma unroll
            for (int mt = 0; mt < 4; ++mt)
                A[s][mt] = *(const v8s*)(sb + s*16384 + (mt*16 + l15)*256 + xorslot);
#pragma unroll 1
            for (int s2 = 0; s2 < 3; ++s2){
                const unsigned short* bp = lbase + (size_t)(((s2*8 + ksg)*16) + w)*512
                                                 + (size_t)l*8;
                v8s B0 = *(const v8s*)(bp);
                v8s B1 = *(const v8s*)(bp + 2048);
                v8s B2 = *(const v8s*)(bp + 4096);
                v8s B3 = *(const v8s*)(bp + 6144);
#pragma unroll
                for (int mt = 0; mt < 4; ++mt){
                    ac[mt][0] = __builtin_amdgcn_mfma_f32_16x16x32_bf16(A[0][mt], B0, ac[mt][0],0,0,0);
                    ac[mt][1] = __builtin_amdgcn_mfma_f32_16x16x32_bf16(A[0][mt], B1, ac[mt][1],0,0,0);
                    ac[mt][2] = __builtin_amdgcn_mfma_f32_16x16x32_bf16(A[0][mt], B2, ac[mt][2],0,0,0);
                    ac[mt][3] = __builtin_amdgcn_mfma_f32_16x16x32_bf16(A[0][mt], B3, ac[mt][3],0,0,0);
                }
                if (s2 < 2){
#pragma unroll
                    for (int mt = 0; mt < 4; ++mt){
                        ac[mt][0] = __builtin_amdgcn_mfma_f32_16x16x32_bf16(A[1][mt], B0, ac[mt][0],0,0,0);
                        ac[mt][1] = __builtin_amdgcn_mfma_f32_16x16x32_bf16(A[1][mt], B1, ac[mt][1],0,0,0);
                        ac[mt][2] = __builtin_amdgcn_mfma_f32_16x16x32_bf16(A[1][mt], B2, ac[mt][2],0,0,0);
                        ac[mt][3] = __builtin_amdgcn_mfma_f32_16x16x32_bf16(A[1][mt], B3, ac[mt][3],0,0,0);
                    }
                }
                if (s2 == 0){
#pragma unroll
                    for (int mt = 0; mt < 4; ++mt){
                        ac[mt][0] = __builtin_amdgcn_mfma_f32_16x16x32_bf16(A[2][mt], B0, ac[mt][0],0,0,0);
                        ac[mt][1] = __builtin_amdgcn_mfma_f32_16x16x32_bf16(A[2][mt], B1, ac[mt][1],0,0,0);
                        ac[mt][2] = __builtin_amdgcn_mfma_f32_16x16x32_bf16(A[2][mt], B2, ac[mt][2],0,0,0);
                        ac[mt][3] = __builtin_amdgcn_mfma_f32_16x16x32_bf16(A[2][mt], B3, ac[mt][3],0,0,0);
                    }
                }
            }
        }
    };

    // C-frag quarter -> bounce. col swizzle bit4 ^= (row>>2)&1 == q&1 here.
    auto bounceWrite = [&](v4f (&ac)[4][4], int p){
        const int colp = (w*16 + l15) ^ ((q & 1) << 4);
#pragma unroll
        for (int mt = 0; mt < 4; ++mt)
#pragma unroll
        for (int j = 0; j < 4; ++j)
            bnc[(mt*16 + q*4 + j)*64 + colp] = ac[mt][p][j];
    };
    auto bounceRead = [&](float (&v)[7][4]){
        const int cl = 4*(t31 & 15);
#pragma unroll
        for (int r = 0; r < 7; ++r){
            const int row = g*7 + r;
            const int sw  = ((row >> 2) & 1) << 4;
            float4 f = *(const float4*)(&bnc[row*64 + (cl ^ sw)]);
            v[r][0]=f.x; v[r][1]=f.y; v[r][2]=f.z; v[r][3]=f.w;
        }
    };

    v4f acc[4][4];
#pragma unroll
    for (int mt=0;mt<4;++mt)
#pragma unroll
    for (int p=0;p<4;++p) acc[mt][p] = (v4f){0.f,0.f,0.f,0.f};

    // ---------------- layer 1: acc = (A1*X) @ W1 ----------------
#pragma unroll
    for (int h = 0; h < 2; ++h){
        {
            float v[7][4];
            const float* xp = X + (node0 + g*7)*HID + h*128 + 4*t31;
#pragma unroll
            for (int r = 0; r < 7; ++r){
                float4 f = *(const float4*)(xp + (long)r*HID);
                v[r][0]=f.x; v[r][1]=f.y; v[r][2]=f.z; v[r][3]=f.w;
            }
            mixA1_4(v);
            writeSplits(v);
        }
        __syncthreads();
        gemm_half(acc, Bw, h);
        __syncthreads();
    }

    // ---------------- layer 2: acc2 = (A1*relu(acc+b1)) @ W2 ----------------
    v4f acc2[4][4];
#pragma unroll
    for (int mt=0;mt<4;++mt)
#pragma unroll
    for (int p=0;p<4;++p) acc2[mt][p] = (v4f){0.f,0.f,0.f,0.f};

#pragma unroll
    for (int h = 0; h < 2; ++h){
#pragma unroll
        for (int sub = 0; sub < 2; ++sub){
            bounceWrite(acc, 2*h + sub);
            __syncthreads();
            if ((t31 >> 4) == sub){
                float v[7][4];
                bounceRead(v);
                const int colg = h*128 + 4*t31;
                float4 bb = *(const float4*)(b1 + colg);
                const float bia[4] = {bb.x, bb.y, bb.z, bb.w};
#pragma unroll
                for (int r = 0; r < 7; ++r)
#pragma unroll
                for (int j = 0; j < 4; ++j)
                    v[r][j] = fmaxf(v[r][j] + bia[j], 0.0f);
                mixA1_4(v);
                writeSplits(v);
            }
            __syncthreads();
        }
        gemm_half(acc2, Bw + 196608, h);
        __syncthreads();
    }

    // ---------------- pm = relu(acc2+b2) @ Wm partials ----------------
    float pm[7][5];
#pragma unroll
    for (int r=0;r<7;++r)
#pragma unroll
    for (int p=0;p<5;++p) pm[r][p] = 0.0f;

#pragma unroll
    for (int h = 0; h < 2; ++h)
#pragma unroll
    for (int sub = 0; sub < 2; ++sub){
        bounceWrite(acc2, 2*h + sub);
        __syncthreads();
        if ((t31 >> 4) == sub){
            float v[7][4];
            bounceRead(v);
            const int colg = h*128 + 4*t31;
            float4 bb = *(const float4*)(b2 + colg);
            const float bia[4] = {bb.x, bb.y, bb.z, bb.w};
#pragma unroll
            for (int r = 0; r < 7; ++r)
#pragma unroll
            for (int j = 0; j < 4; ++j)
                v[r][j] = fmaxf(v[r][j] + bia[j], 0.0f);
#pragma unroll
            for (int j = 0; j < 4; ++j){
                const float* wr = Wm + (colg + j)*5;
                float w5[5];
#pragma unroll
                for (int p = 0; p < 5; ++p) w5[p] = wr[p];
#pragma unroll
                for (int r = 0; r < 7; ++r)
#pragma unroll
                for (int p = 0; p < 5; ++p)
                    pm[r][p] = fmaf(v[r][j], w5[p], pm[r][p]);
            }
        }
        __syncthreads();
    }

    // reduce pm across the 32 lanes of each graph-group (masks <32 stay in half)
#pragma unroll
    for (int m = 16; m >= 1; m >>= 1)
#pragma unroll
        for (int r = 0; r < 7; ++r)
#pragma unroll
            for (int p = 0; p < 5; ++p)
                pm[r][p] += __shfl_xor(pm[r][p], m, 64);

    // ---------------- finalize: A2 prefix mix + bm + gumbel + hard argmax ----
    if (t31 < 7){
        const int rr = t31;
        const long node = node0 + g*7 + rr;
        const float d2r = d2c(rr);
        float op[5];
#pragma unroll
        for (int p = 0; p < 5; ++p) op[p] = bm[p];
#pragma unroll
        for (int i = 0; i < 7; ++i){
            const float wgt = (i > rr) ? 0.0f
                            : (((i < rr) ? 0.5f : 1.0f) * d2c(i) * d2r);
#pragma unroll
            for (int p = 0; p < 5; ++p)
                op[p] = fmaf(wgt, pm[i][p], op[p]);
        }
        const float* gp = g_op + node*5;
        float best = op[0] + gp[0];
        int bi = 0;
#pragma unroll
        for (int p = 1; p < 5; ++p){
            float u = op[p] + gp[p];
            if (u > best) { best = u; bi = p; }   // strict > == jnp.argmax first-max
        }
        float* o = out + node*5;
#pragma unroll
        for (int p = 0; p < 5; ++p) o[p] = (p == bi) ? 1.0f : 0.0f;
    }
}

extern "C" void kernel_launch(void* const* d_in, const int* in_sizes, int n_in,
                              void* d_out, int out_size, void* d_ws, size_t ws_size,
                              hipStream_t stream)
{
    const float* X   = (const float*)d_in[0];
    // d_in[1] edge_index, d_in[2] batch: compile-time-constant structure
    const float* W1  = (const float*)d_in[3];
    const float* b1  = (const float*)d_in[4];
    const float* W2  = (const float*)d_in[5];
    const float* b2  = (const float*)d_in[6];
    // d_in[7] We, d_in[8] be, d_in[11] g_edge: dead (avg_scores == 0.5)
    const float* Wm  = (const float*)d_in[9];
    const float* bm  = (const float*)d_in[10];
    const float* gop = (const float*)d_in[12];
    float* out = (float*)d_out;

    unsigned short* wsplit = (unsigned short*)d_ws;   // 2*3*8*16*64*8*2B = 768 KB

    prep_w<<<192, 256, 0, stream>>>(W1, W2, wsplit);

    const int N       = in_sizes[0] / HID;  // 140000 nodes
    const int ngraph  = N / 7;              // 20000
    const int nblocks = ngraph / 8;         // 2500 blocks of 256 threads

    nas_mfma<<<nblocks, 256, 0, stream>>>(X, b1, b2, Wm, bm, gop, wsplit, out);
}

// Round 3
// 400.643 us; speedup vs baseline: 1.5817x; 1.1012x over previous
//
#include <hip/hip_runtime.h>
#include <math.h>

#define HID 256

typedef __attribute__((ext_vector_type(8))) short v8s;   // 8 bf16 (4 VGPRs)
typedef __attribute__((ext_vector_type(4))) float v4f;   // MFMA accumulator

__device__ __forceinline__ float d1c(int i){ return 1.0f/sqrtf((float)(i+1)); }
__device__ __forceinline__ float d2c(int i){ return 1.0f/sqrtf(1.0f+0.5f*(float)i); }

// round-to-nearest-even float -> bf16 (bit pattern)
__device__ __forceinline__ unsigned short f2bf(float x){
    unsigned u = __float_as_uint(x);
    u += 0x7fffu + ((u>>16)&1u);
    return (unsigned short)(u>>16);
}
__device__ __forceinline__ float bf2f(unsigned short b){
    return __uint_as_float(((unsigned)b)<<16);
}

// in-place descending prefix mix: v[r] = sum_{i<=r} d1[i]*d1[r]*v[i]
__device__ __forceinline__ void mixA1_4(float (&v)[7][4]) {
#pragma unroll
    for (int r = 6; r >= 0; --r) {
        float t[4] = {0, 0, 0, 0};
#pragma unroll
        for (int i = 0; i <= r; ++i) {
            const float c = d1c(i) * d1c(r);
#pragma unroll
            for (int j = 0; j < 4; ++j) t[j] = fmaf(c, v[i][j], t[j]);
        }
#pragma unroll
        for (int j = 0; j < 4; ++j) v[r][j] = t[j];
    }
}

// ---------------- prep: pack W1,W2 3-term bf16 splits in B-fragment order ----
// layout: [L(2)][s(3)][k0(8)][nt(16)][lane(64)][e(8)] bf16, linear in tid.
// value = w_s[k0*32 + 8*(lane>>4) + e][nt*16 + (lane&15)]
__global__ void prep_w(const float* __restrict__ W1, const float* __restrict__ W2,
                       unsigned short* __restrict__ outw)
{
    const int tid = blockIdx.x*256 + threadIdx.x;
    if (tid >= 2*3*8*16*64) return;
    const int l  = tid & 63;
    const int c  = tid >> 6;
    const int nt = c & 15;
    const int k0 = (c>>4) & 7;
    const int s  = (c>>7) % 3;
    const int L  = c / (3*8*16);
    const float* W = L ? W2 : W1;
    const int n = nt*16 + (l & 15);
    unsigned short* o = outw + (size_t)tid*8;
#pragma unroll
    for (int e = 0; e < 8; ++e){
        const int k = k0*32 + (l>>4)*8 + e;
        float x = W[k*HID + n];
        unsigned short b0 = f2bf(x); float rr = x - bf2f(b0);
        unsigned short b1 = f2bf(rr); rr -= bf2f(b1);
        unsigned short b2 = f2bf(rr);
        o[e] = (s==0)? b0 : (s==1)? b1 : b2;
    }
}

// ---------------- main fused kernel ----------------------------------------
// 256 threads = 4 waves; 8 graphs (56 rows, rows 56-63 of M unused).
// Each wave owns N-tiles {w, 4+w, 8+w, 12+w} (acc[mt][p], ntile = 4p+w).
// bf16 MFMA with 3-term error-compensated splits (6 products, s1+s2<=2).
// v3 schedule changes (data layout & FP order identical to v2):
//  - gemm_half software-pipelined: B-fragment ring (3 groups, prefetch 2 ahead)
//    hides L2 latency under MFMA clusters; fully unrolled (static indices).
//  - 32KB full-half bounce: ALL threads stage in one phase (barriers 20 -> ~13).
//  - X h1 and layer-boundary h1 held in registers across gemm(h0).
// LDS 48KB splits + 32KB bounce = 80KB -> 2 blocks/CU.
__global__ __launch_bounds__(256, 2)
void nas_mfma(const float* __restrict__ X,
              const float* __restrict__ b1, const float* __restrict__ b2,
              const float* __restrict__ Wm, const float* __restrict__ bm,
              const float* __restrict__ g_op,
              const unsigned short* __restrict__ Bw,
              float* __restrict__ out)
{
    __shared__ __align__(16) char smem[49152 + 32768];
    char*  sb  = smem;                       // splits[3][64 rows][128 k] bf16
    float* bnc = (float*)(smem + 49152);     // bounce [64 rows][128 cols] f32

    const int t   = threadIdx.x;
    const int w   = t >> 6;          // wave 0..3
    const int l   = t & 63;
    const int l15 = l & 15;
    const int q   = l >> 4;
    const int g   = t >> 5;          // graph 0..7
    const int t31 = t & 31;
    const long node0 = (long)blockIdx.x * 56;

    // write 3-term splits of v[7][4] for k-local cols 4*t31..+3, rows 7g..7g+6.
    // slot swizzle: physical 16B slot = (k>>3) ^ (row&7); contents stay k-ordered.
    auto writeSplits = [&](const float (&v)[7][4]){
        const int kl   = 4*t31;
        const int hs   = kl >> 3;
        const int sub8 = (kl & 7) * 2;
#pragma unroll
        for (int r = 0; r < 7; ++r){
            const int row  = g*7 + r;
            const int slot = hs ^ (row & 7);
            char* p = sb + row*256 + slot*16 + sub8;
            unsigned short h0[4], h1[4], h2[4];
#pragma unroll
            for (int j = 0; j < 4; ++j){
                float x = v[r][j];
                h0[j] = f2bf(x); float rr = x - bf2f(h0[j]);
                h1[j] = f2bf(rr); rr -= bf2f(h1[j]);
                h2[j] = f2bf(rr);
            }
            *(uint2*)(p)         = make_uint2((unsigned)h0[0]|((unsigned)h0[1]<<16),
                                              (unsigned)h0[2]|((unsigned)h0[3]<<16));
            *(uint2*)(p+16384)   = make_uint2((unsigned)h1[0]|((unsigned)h1[1]<<16),
                                              (unsigned)h1[2]|((unsigned)h1[3]<<16));
            *(uint2*)(p+32768)   = make_uint2((unsigned)h2[0]|((unsigned)h2[1]<<16),
                                              (unsigned)h2[2]|((unsigned)h2[3]<<16));
        }
    };

    // one k-half of a split GEMM, software-pipelined.
    // Product order identical to v2: per ks, per s2 in 0..2, per s1 <= 2-s2.
    auto gemm_half = [&](v4f (&ac)[4][4], const unsigned short* lbase, int h){
        const unsigned short* bbase = lbase + (size_t)w*512 + (size_t)l*8;
        v8s Bb[3][4];                          // ring of 3 (ks,s2)-groups
        v8s A[3][4];
        auto loadB = [&](int gi, int buf){
            const int ks = gi / 3, s2 = gi % 3;
            const unsigned short* bp = bbase + (size_t)((s2*8 + h*4 + ks)*16)*512;
            Bb[buf][0] = *(const v8s*)(bp);
            Bb[buf][1] = *(const v8s*)(bp + 2048);
            Bb[buf][2] = *(const v8s*)(bp + 4096);
            Bb[buf][3] = *(const v8s*)(bp + 6144);
        };
        loadB(0, 0);
        loadB(1, 1);
#pragma unroll
        for (int gi = 0; gi < 12; ++gi){
            const int ks = gi / 3, s2 = gi % 3;
            if (s2 == 0){
                const int xorslot = ((ks*4 + q) ^ (l & 7)) << 4;
#pragma unroll
                for (int s = 0; s < 3; ++s)
#pragma unroll
                for (int mt = 0; mt < 4; ++mt)
                    A[s][mt] = *(const v8s*)(sb + s*16384 + (mt*16 + l15)*256 + xorslot);
            }
            if (gi + 2 < 12) loadB(gi + 2, (gi + 2) % 3);
            const int buf = gi % 3;
#pragma unroll
            for (int s1 = 0; s1 < 3; ++s1){
                if (s1 + s2 > 2) continue;
#pragma unroll
                for (int mt = 0; mt < 4; ++mt){
                    ac[mt][0] = __builtin_amdgcn_mfma_f32_16x16x32_bf16(A[s1][mt], Bb[buf][0], ac[mt][0],0,0,0);
                    ac[mt][1] = __builtin_amdgcn_mfma_f32_16x16x32_bf16(A[s1][mt], Bb[buf][1], ac[mt][1],0,0,0);
                    ac[mt][2] = __builtin_amdgcn_mfma_f32_16x16x32_bf16(A[s1][mt], Bb[buf][2], ac[mt][2],0,0,0);
                    ac[mt][3] = __builtin_amdgcn_mfma_f32_16x16x32_bf16(A[s1][mt], Bb[buf][3], ac[mt][3],0,0,0);
                }
            }
        }
    };

    // bounce write: half h (output quarters p=2h, 2h+1) -> bnc[64][128].
    // addr = row*128 + (lc ^ swz(row)), swz = ((q&1)<<4)^((q>>1)<<2), q=(row>>2)&3
    // -> 2 lanes/bank (free) on write, b128-min on read.
    auto bw2 = [&](const v4f (&ac)[4][4], int h){
#pragma unroll
        for (int pb = 0; pb < 2; ++pb){
            const int p  = 2*h + pb;
            const int lc = (w + 4*pb)*16 + l15;
#pragma unroll
            for (int mt = 0; mt < 4; ++mt){
                const int sw = ((q&1)<<4) ^ ((q>>1)<<2);
#pragma unroll
                for (int j = 0; j < 4; ++j){
                    const int row = mt*16 + q*4 + j;
                    bnc[row*128 + (lc ^ sw)] = ac[mt][p][j];
                }
            }
        }
    };
    auto br2 = [&](float (&v)[7][4]){
        const int lc = 4*t31;
#pragma unroll
        for (int r = 0; r < 7; ++r){
            const int row = g*7 + r;
            const int qq  = (row>>2)&3;
            const int sw  = ((qq&1)<<4) ^ ((qq>>1)<<2);
            float4 f = *(const float4*)(&bnc[row*128 + (lc ^ sw)]);
            v[r][0]=f.x; v[r][1]=f.y; v[r][2]=f.z; v[r][3]=f.w;
        }
    };
    auto biasRelu = [&](float (&v)[7][4], const float* bias, int h){
        float4 bb = *(const float4*)(bias + h*128 + 4*t31);
        const float bia[4] = {bb.x, bb.y, bb.z, bb.w};
#pragma unroll
        for (int r = 0; r < 7; ++r)
#pragma unroll
        for (int j = 0; j < 4; ++j)
            v[r][j] = fmaxf(v[r][j] + bia[j], 0.0f);
    };

    // ---------------- layer 1: acc = (A1*X) @ W1 ----------------
    v4f acc[4][4];
#pragma unroll
    for (int mt=0;mt<4;++mt)
#pragma unroll
    for (int p=0;p<4;++p) acc[mt][p] = (v4f){0.f,0.f,0.f,0.f};

    float vh1[7][4];
    {
        float v0[7][4];
        const float* xp = X + (node0 + g*7)*HID + 4*t31;
#pragma unroll
        for (int r = 0; r < 7; ++r){
            float4 f0 = *(const float4*)(xp + (long)r*HID);
            float4 f1 = *(const float4*)(xp + (long)r*HID + 128);
            v0[r][0]=f0.x; v0[r][1]=f0.y; v0[r][2]=f0.z; v0[r][3]=f0.w;
            vh1[r][0]=f1.x; vh1[r][1]=f1.y; vh1[r][2]=f1.z; vh1[r][3]=f1.w;
        }
        mixA1_4(v0);
        mixA1_4(vh1);
        writeSplits(v0);
    }
    __syncthreads();
    gemm_half(acc, Bw, 0);              // vh1 (28 regs) live across this
    __syncthreads();
    writeSplits(vh1);
    __syncthreads();
    gemm_half(acc, Bw, 1);

    // ---------------- boundary 1: P2 = A1*relu(acc+b1); acc2 = P2 @ W2 ------
    v4f acc2[4][4];
#pragma unroll
    for (int mt=0;mt<4;++mt)
#pragma unroll
    for (int p=0;p<4;++p) acc2[mt][p] = (v4f){0.f,0.f,0.f,0.f};

    __syncthreads();                    // gemm reads of sb done
    bw2(acc, 0);
    __syncthreads();
    {
        float v[7][4];
        br2(v);
        biasRelu(v, b1, 0);
        mixA1_4(v);
        writeSplits(v);
    }
    __syncthreads();                    // bnc consumed, sb(h0) ready
    bw2(acc, 1);
    __syncthreads();
    br2(vh1);                           // h1 half -> registers
    biasRelu(vh1, b1, 1);
    mixA1_4(vh1);
    gemm_half(acc2, Bw + 196608, 0);    // reads sb(h0); vh1 live in regs
    __syncthreads();
    writeSplits(vh1);
    __syncthreads();
    gemm_half(acc2, Bw + 196608, 1);

    // ---------------- pm = relu(acc2+b2) @ Wm partials ----------------------
    float pm[7][5];
#pragma unroll
    for (int r=0;r<7;++r)
#pragma unroll
    for (int p=0;p<5;++p) pm[r][p] = 0.0f;

    auto stage_pm = [&](int h){
        float v[7][4];
        br2(v);
        biasRelu(v, b2, h);
        const int colg = h*128 + 4*t31;
#pragma unroll
        for (int j = 0; j < 4; ++j){
            const float* wr = Wm + (colg + j)*5;
            float w5[5];
#pragma unroll
            for (int p = 0; p < 5; ++p) w5[p] = wr[p];
#pragma unroll
            for (int r = 0; r < 7; ++r)
#pragma unroll
            for (int p = 0; p < 5; ++p)
                pm[r][p] = fmaf(v[r][j], w5[p], pm[r][p]);
        }
    };

    __syncthreads();                    // gemm reads of sb done
    bw2(acc2, 0);
    __syncthreads();
    stage_pm(0);
    __syncthreads();
    bw2(acc2, 1);
    __syncthreads();
    stage_pm(1);

    // reduce pm across the 32 lanes of each graph-group (masks <32 stay in half)
#pragma unroll
    for (int m = 16; m >= 1; m >>= 1)
#pragma unroll
        for (int r = 0; r < 7; ++r)
#pragma unroll
            for (int p = 0; p < 5; ++p)
                pm[r][p] += __shfl_xor(pm[r][p], m, 64);

    // ---------------- finalize: A2 prefix mix + bm + gumbel + hard argmax ----
    if (t31 < 7){
        const int rr = t31;
        const long node = node0 + g*7 + rr;
        const float d2r = d2c(rr);
        float op[5];
#pragma unroll
        for (int p = 0; p < 5; ++p) op[p] = bm[p];
#pragma unroll
        for (int i = 0; i < 7; ++i){
            const float wgt = (i > rr) ? 0.0f
                            : (((i < rr) ? 0.5f : 1.0f) * d2c(i) * d2r);
#pragma unroll
            for (int p = 0; p < 5; ++p)
                op[p] = fmaf(wgt, pm[i][p], op[p]);
        }
        const float* gp = g_op + node*5;
        float best = op[0] + gp[0];
        int bi = 0;
#pragma unroll
        for (int p = 1; p < 5; ++p){
            float u = op[p] + gp[p];
            if (u > best) { best = u; bi = p; }   // strict > == jnp.argmax first-max
        }
        float* o = out + node*5;
#pragma unroll
        for (int p = 0; p < 5; ++p) o[p] = (p == bi) ? 1.0f : 0.0f;
    }
}

extern "C" void kernel_launch(void* const* d_in, const int* in_sizes, int n_in,
                              void* d_out, int out_size, void* d_ws, size_t ws_size,
                              hipStream_t stream)
{
    const float* X   = (const float*)d_in[0];
    // d_in[1] edge_index, d_in[2] batch: compile-time-constant structure
    const float* W1  = (const float*)d_in[3];
    const float* b1  = (const float*)d_in[4];
    const float* W2  = (const float*)d_in[5];
    const float* b2  = (const float*)d_in[6];
    // d_in[7] We, d_in[8] be, d_in[11] g_edge: dead (avg_scores == 0.5)
    const float* Wm  = (const float*)d_in[9];
    const float* bm  = (const float*)d_in[10];
    const float* gop = (const float*)d_in[12];
    float* out = (float*)d_out;

    unsigned short* wsplit = (unsigned short*)d_ws;   // 2*3*8*16*64*8*2B = 768 KB

    prep_w<<<192, 256, 0, stream>>>(W1, W2, wsplit);

    const int N       = in_sizes[0] / HID;  // 140000 nodes
    const int ngraph  = N / 7;              // 20000
    const int nblocks = ngraph / 8;         // 2500 blocks of 256 threads

    nas_mfma<<<nblocks, 256, 0, stream>>>(X, b1, b2, Wm, bm, gop, wsplit, out);
}